// Round 1
// baseline (373.742 us; speedup 1.0000x reference)
//
#include <hip/hip_runtime.h>
#include <math.h>

#define SEQ   2048
#define BATCH 32
#define HID   1024
#define RPW   16                        // seq rows per wave (was 32: double the grid for occupancy)
#define WPB   4                         // waves per block (independent)
#define WAVES_PER_B  (SEQ / RPW)        // 128 partials per batch
#define BLOCKS_PER_B (WAVES_PER_B / WPB) // 32

typedef float vf4 __attribute__((ext_vector_type(4)));

// ---------------------------------------------------------------------------
// Kernel A: wave-autonomous flash partial. No LDS, no barriers.
// Wave handles batch b, rows s0..s0+15. Lane owns columns {4*(lane+64j)} j<4.
// Dot reduced with a 6-step shuffle butterfly (score becomes wave-uniform),
// single-exp online softmax, next-row prefetch keeps loads in flight.
// vs previous version: RPW 32->16 (4096 waves = 4 waves/SIMD instead of 2),
// plain (cache-allocating) loads instead of nontemporal, launch_bounds(256,4)
// to hold VGPRs under 128 so the 4-wave/SIMD occupancy is actually reached.
// ---------------------------------------------------------------------------
__global__ __launch_bounds__(256, 4) void attn_partial(
    const float* __restrict__ rnn_out,   // [S, B, H]
    const float* __restrict__ state,     // [2, 2, B, H/2]
    float* __restrict__ o_part,          // [B*WAVES_PER_B, H]
    float* __restrict__ m_part,          // [B*WAVES_PER_B]
    float* __restrict__ l_part)          // [B*WAVES_PER_B]
{
    const int b     = blockIdx.x / BLOCKS_PER_B;
    const int slice = blockIdx.x % BLOCKS_PER_B;
    const int lane  = threadIdx.x & 63;
    const int wav   = threadIdx.x >> 6;
    const int wid   = slice * WPB + wav;       // 0..127
    const int s0    = wid * RPW;

    // merged[b][h] = state[1][h/512][b][h%512]; lane's 4 vf4 slices
    vf4 mrg[4];
    #pragma unroll
    for (int j = 0; j < 4; ++j) {
        const int h   = 4 * (lane + 64 * j);
        const int dir = h >> 9;
        const int k   = h & 511;
        mrg[j] = *(const vf4*)(state + ((size_t)(2 + dir) * BATCH + b) * 512 + k);
    }

    const size_t row_stride = (size_t)BATCH * HID;
    const float* base = rnn_out + ((size_t)s0 * BATCH + b) * HID + 4 * lane;

    vf4 cur[4], nxt[4];
    #pragma unroll
    for (int j = 0; j < 4; ++j)
        cur[j] = *(const vf4*)(base + 256 * j);

    float m = -INFINITY, l = 0.f;
    vf4 acc[4];
    #pragma unroll
    for (int j = 0; j < 4; ++j) acc[j] = (vf4)(0.f);

    for (int i = 0; i < RPW; ++i) {
        // prefetch next row while we reduce the current one
        if (i + 1 < RPW) {
            const float* nb = base + (size_t)(i + 1) * row_stride;
            #pragma unroll
            for (int j = 0; j < 4; ++j)
                nxt[j] = *(const vf4*)(nb + 256 * j);
        }

        float d = 0.f;
        #pragma unroll
        for (int j = 0; j < 4; ++j) {
            const vf4 p = cur[j] * mrg[j];
            d += p.x + p.y + p.z + p.w;
        }
        #pragma unroll
        for (int off = 1; off < 64; off <<= 1)
            d += __shfl_xor(d, off, 64);       // all lanes hold the full dot

        // single-exp online update; d wave-uniform -> uniform scalar branch
        if (d > m) {
            const float alpha = __expf(m - d); // exp(-inf)=0 on first row
            l = l * alpha + 1.f;               // p == exp(d - d) == 1
            #pragma unroll
            for (int j = 0; j < 4; ++j)
                acc[j] = acc[j] * alpha + cur[j];
            m = d;
        } else {
            const float p = __expf(d - m);
            l += p;
            #pragma unroll
            for (int j = 0; j < 4; ++j)
                acc[j] += p * cur[j];
        }
        #pragma unroll
        for (int j = 0; j < 4; ++j) cur[j] = nxt[j];
    }

    float* op = o_part + (size_t)(b * WAVES_PER_B + wid) * HID + 4 * lane;
    #pragma unroll
    for (int j = 0; j < 4; ++j) *(vf4*)(op + 256 * j) = acc[j];
    if (lane == 0) {
        m_part[b * WAVES_PER_B + wid] = m;
        l_part[b * WAVES_PER_B + wid] = l;
    }
}

// ---------------------------------------------------------------------------
// Kernel B: combine the 128 wave-partials per batch (16.8 MB, mostly L2/L3-hit).
// Grid = B * (HID/64) = 512 blocks; 16 chunk-ways x 16 vf4-cols per block.
// ---------------------------------------------------------------------------
#define NCH WAVES_PER_B   // 128
__global__ __launch_bounds__(256) void attn_combine(
    const float* __restrict__ o_part,    // [B*NCH, H]
    const float* __restrict__ m_part,
    const float* __restrict__ l_part,
    float* __restrict__ out)             // [B, H]
{
    const int b  = blockIdx.x / (HID / 64);
    const int hs = blockIdx.x % (HID / 64);
    const int t  = threadIdx.x;
    const int cg  = t & 15;
    const int way = t >> 4;
    const int h  = hs * 64 + cg * 4;

    const float* mp = m_part + b * NCH;
    const float* lp = l_part + b * NCH;
    float M = -INFINITY;
    for (int c = 0; c < NCH; ++c) M = fmaxf(M, mp[c]);
    float L = 0.f;
    for (int c = 0; c < NCH; ++c) L += lp[c] * __expf(mp[c] - M);
    const float invL = 1.f / L;

    vf4 acc = (vf4)(0.f);
    for (int c = way; c < NCH; c += 16) {
        const float w = __expf(mp[c] - M) * invL;
        const vf4 o = *(const vf4*)(o_part + (size_t)(b * NCH + c) * HID + h);
        acc += w * o;
    }

    __shared__ vf4 red[16][16];
    red[way][cg] = acc;
    __syncthreads();
    if (way == 0) {
        vf4 r = red[0][cg];
        #pragma unroll
        for (int wy = 1; wy < 16; ++wy)
            r += red[wy][cg];
        *(vf4*)(out + (size_t)b * HID + h) = r;
    }
}

extern "C" void kernel_launch(void* const* d_in, const int* in_sizes, int n_in,
                              void* d_out, int out_size, void* d_ws, size_t ws_size,
                              hipStream_t stream) {
    const float* rnn_out = (const float*)d_in[0];   // [2048, 32, 1024] f32
    const float* state   = (const float*)d_in[1];   // [2, 2, 32, 512]  f32
    float* out = (float*)d_out;                     // [32, 1024, 1]    f32

    float* o_part = (float*)d_ws;                                        // 16.8 MiB
    float* m_part = (float*)((char*)d_ws + (size_t)BATCH * NCH * HID * 4);
    float* l_part = m_part + BATCH * NCH;

    attn_partial<<<BATCH * BLOCKS_PER_B, 256, 0, stream>>>(rnn_out, state, o_part, m_part, l_part);
    attn_combine<<<BATCH * (HID / 64), 256, 0, stream>>>(o_part, m_part, l_part, out);
}